// Round 1
// baseline (829.245 us; speedup 1.0000x reference)
//
#include <hip/hip_runtime.h>
#include <math.h>

#define SDIM 2048
#define HDIM 2048
#define LNUM 2
#define ANUM 16

__device__ __forceinline__ float wave_sum(float v) {
#pragma unroll
    for (int off = 32; off > 0; off >>= 1) v += __shfl_down(v, off, 64);
    return v;
}

__device__ __forceinline__ float wave_max(float v) {
#pragma unroll
    for (int off = 32; off > 0; off >>= 1) v = fmaxf(v, __shfl_down(v, off, 64));
    return v;
}

__device__ __forceinline__ float dot4(float4 a, float4 b) {
    return a.x * b.x + a.y * b.y + a.z * b.z + a.w * b.w;
}

// Zero h(ping buffer 0) and c, copy x -> xcur. Workspace is poisoned 0xAA;
// we must init everything we read. Runs every kernel_launch (deterministic).
__global__ __launch_bounds__(256) void init_kernel(
    const float* __restrict__ x, float* __restrict__ xcur,
    float* __restrict__ h0, float* __restrict__ c)
{
    int i = blockIdx.x * 256 + threadIdx.x;   // grid covers LNUM*HDIM = 4096
    if (i < LNUM * HDIM) { h0[i] = 0.f; c[i] = 0.f; }
    if (i < SDIM) xcur[i] = x[i];
}

// One LSTM layer, one timestep. Block j computes gate rows {j, j+H, j+2H, j+3H}
// of gates = Wih@inp + bih + Whh@hin + bhh, then the pointwise cell update.
// c is read/written only at index j by block j -> safe in place.
// hout must be a different buffer than hin (ping-pong across steps).
__global__ __launch_bounds__(256) void lstm_layer_kernel(
    const float* __restrict__ inp, const float* __restrict__ hin,
    float* __restrict__ hout, float* __restrict__ cst,
    const float* __restrict__ Wih, const float* __restrict__ Whh,
    const float* __restrict__ bih, const float* __restrict__ bhh)
{
    const int j = blockIdx.x;       // 0..HDIM-1
    const int t = threadIdx.x;      // 0..255

    const float4* inp4 = (const float4*)inp;
    const float4* hin4 = (const float4*)hin;
    const float4 x0 = inp4[t],       x1 = inp4[256 + t];
    const float4 h0 = hin4[t],       h1 = hin4[256 + t];

    float acc[4];
#pragma unroll
    for (int g = 0; g < 4; ++g) {
        const float4* wi4 = (const float4*)(Wih + (size_t)(g * HDIM + j) * HDIM);
        const float4* wh4 = (const float4*)(Whh + (size_t)(g * HDIM + j) * HDIM);
        float4 wa = wi4[t], wb = wi4[256 + t];
        float4 wc = wh4[t], wd = wh4[256 + t];
        acc[g] = dot4(wa, x0) + dot4(wb, x1) + dot4(wc, h0) + dot4(wd, h1);
    }

    __shared__ float red[4][4];     // [wave][gate]
    const int wave = t >> 6, lane = t & 63;
#pragma unroll
    for (int g = 0; g < 4; ++g) {
        float v = wave_sum(acc[g]);
        if (lane == 0) red[wave][g] = v;
    }
    __syncthreads();
    if (t == 0) {
        float gi = red[0][0] + red[1][0] + red[2][0] + red[3][0] + bih[0 * HDIM + j] + bhh[0 * HDIM + j];
        float gf = red[0][1] + red[1][1] + red[2][1] + red[3][1] + bih[1 * HDIM + j] + bhh[1 * HDIM + j];
        float gg = red[0][2] + red[1][2] + red[2][2] + red[3][2] + bih[2 * HDIM + j] + bhh[2 * HDIM + j];
        float go = red[0][3] + red[1][3] + red[2][3] + red[3][3] + bih[3 * HDIM + j] + bhh[3 * HDIM + j];
        float si = 1.f / (1.f + expf(-gi));
        float sf = 1.f / (1.f + expf(-gf));
        float so = 1.f / (1.f + expf(-go));
        float tg = tanhf(gg);
        float cn = sf * cst[j] + si * tg;
        cst[j]  = cn;
        hout[j] = so * tanhf(cn);
    }
}

// logits[r] = Wout[r,:] @ h + bout[r]; one row per block.
__global__ __launch_bounds__(256) void out_gemv_kernel(
    const float* __restrict__ h, const float* __restrict__ Wout,
    const float* __restrict__ bout, float* __restrict__ logits)
{
    const int r = blockIdx.x, t = threadIdx.x;
    const float4* w4 = (const float4*)(Wout + (size_t)r * HDIM);
    const float4* h4 = (const float4*)h;
    float v = dot4(w4[t], h4[t]) + dot4(w4[256 + t], h4[256 + t]);
    __shared__ float red[4];
    v = wave_sum(v);
    if ((t & 63) == 0) red[t >> 6] = v;
    __syncthreads();
    if (t == 0) logits[r] = red[0] + red[1] + red[2] + red[3] + bout[r];
}

// Single-block softmax over 2048 logits; writes next input AND d_out[step].
__global__ __launch_bounds__(256) void softmax_kernel(
    const float* __restrict__ logits, float* __restrict__ xcur,
    float* __restrict__ outp)
{
    const int t = threadIdx.x;
    const float4* l4 = (const float4*)logits;
    float4 v0 = l4[t], v1 = l4[256 + t];

    float m = fmaxf(fmaxf(fmaxf(v0.x, v0.y), fmaxf(v0.z, v0.w)),
                    fmaxf(fmaxf(v1.x, v1.y), fmaxf(v1.z, v1.w)));
    __shared__ float red[4];
    __shared__ float bc;
    m = wave_max(m);
    if ((t & 63) == 0) red[t >> 6] = m;
    __syncthreads();
    if (t == 0) bc = fmaxf(fmaxf(red[0], red[1]), fmaxf(red[2], red[3]));
    __syncthreads();
    m = bc;

    float4 e0, e1;
    e0.x = expf(v0.x - m); e0.y = expf(v0.y - m); e0.z = expf(v0.z - m); e0.w = expf(v0.w - m);
    e1.x = expf(v1.x - m); e1.y = expf(v1.y - m); e1.z = expf(v1.z - m); e1.w = expf(v1.w - m);
    float s = e0.x + e0.y + e0.z + e0.w + e1.x + e1.y + e1.z + e1.w;
    s = wave_sum(s);
    if ((t & 63) == 0) red[t >> 6] = s;
    __syncthreads();
    if (t == 0) bc = red[0] + red[1] + red[2] + red[3];
    __syncthreads();
    const float inv = 1.f / bc;

    float4 p0, p1;
    p0.x = e0.x * inv; p0.y = e0.y * inv; p0.z = e0.z * inv; p0.w = e0.w * inv;
    p1.x = e1.x * inv; p1.y = e1.y * inv; p1.z = e1.z * inv; p1.w = e1.w * inv;
    ((float4*)xcur)[t]       = p0;
    ((float4*)xcur)[256 + t] = p1;
    ((float4*)outp)[t]       = p0;
    ((float4*)outp)[256 + t] = p1;
}

extern "C" void kernel_launch(void* const* d_in, const int* in_sizes, int n_in,
                              void* d_out, int out_size, void* d_ws, size_t ws_size,
                              hipStream_t stream) {
    const float* x    = (const float*)d_in[0];
    const float* Wih  = (const float*)d_in[1];   // [L, 4H, H]
    const float* Whh  = (const float*)d_in[2];   // [L, 4H, H]
    const float* bih  = (const float*)d_in[3];   // [L, 4H]
    const float* bhh  = (const float*)d_in[4];   // [L, 4H]
    const float* Wout = (const float*)d_in[5];   // [S, H]
    const float* bout = (const float*)d_in[6];   // [S]
    float* out = (float*)d_out;                  // [A, S] fp32

    float* ws     = (float*)d_ws;
    float* xcur   = ws;                          // 2048
    float* hb     = ws + SDIM;                   // ping-pong h: 2 * L * H = 8192
    float* c      = hb + 2 * LNUM * HDIM;        // L * H = 4096
    float* logits = c + LNUM * HDIM;             // 2048

    const size_t wstride = (size_t)4 * HDIM * HDIM;  // per-layer W_ih/W_hh stride
    const size_t bstride = (size_t)4 * HDIM;

    init_kernel<<<16, 256, 0, stream>>>(x, xcur, hb, c);

    for (int s = 0; s < ANUM; ++s) {
        const int cur = s & 1, nxt = cur ^ 1;
        float* h0in  = hb + cur * (LNUM * HDIM);
        float* h0out = hb + nxt * (LNUM * HDIM);
        float* h1in  = h0in + HDIM;
        float* h1out = h0out + HDIM;

        lstm_layer_kernel<<<HDIM, 256, 0, stream>>>(
            xcur, h0in, h0out, c, Wih, Whh, bih, bhh);
        lstm_layer_kernel<<<HDIM, 256, 0, stream>>>(
            h0out, h1in, h1out, c + HDIM,
            Wih + wstride, Whh + wstride, bih + bstride, bhh + bstride);
        out_gemv_kernel<<<SDIM, 256, 0, stream>>>(h1out, Wout, bout, logits);
        softmax_kernel<<<1, 256, 0, stream>>>(logits, xcur, out + (size_t)s * SDIM);
    }
}

// Round 2
// 625.386 us; speedup vs baseline: 1.3260x; 1.3260x over previous
//
#include <hip/hip_runtime.h>
#include <hip/hip_fp16.h>
#include <math.h>

#define SDIM 2048
#define HDIM 2048
#define LNUM 2
#define ANUM 16

__device__ __forceinline__ float wave_sum(float v) {
#pragma unroll
    for (int off = 32; off > 0; off >>= 1) v += __shfl_down(v, off, 64);
    return v;
}

__device__ __forceinline__ float wave_max(float v) {
#pragma unroll
    for (int off = 32; off > 0; off >>= 1) v = fmaxf(v, __shfl_down(v, off, 64));
    return v;
}

// Convert fp32 -> fp16, 8 elements per thread (read 2 float4, write 1 uint4).
__global__ __launch_bounds__(256) void f32_to_f16_kernel(
    const float4* __restrict__ src, uint4* __restrict__ dst, int n8)
{
    int i = blockIdx.x * 256 + threadIdx.x;
    const int stride = gridDim.x * 256;
    for (; i < n8; i += stride) {
        float4 a = src[2 * i], b = src[2 * i + 1];
        __half2 p0 = __floats2half2_rn(a.x, a.y);
        __half2 p1 = __floats2half2_rn(a.z, a.w);
        __half2 p2 = __floats2half2_rn(b.x, b.y);
        __half2 p3 = __floats2half2_rn(b.z, b.w);
        uint4 o;
        o.x = *(unsigned int*)&p0;
        o.y = *(unsigned int*)&p1;
        o.z = *(unsigned int*)&p2;
        o.w = *(unsigned int*)&p3;
        dst[i] = o;
    }
}

// Zero h(ping buffer 0) and c, copy x -> xcur.
__global__ __launch_bounds__(256) void init_kernel(
    const float* __restrict__ x, float* __restrict__ xcur,
    float* __restrict__ h0, float* __restrict__ c)
{
    int i = blockIdx.x * 256 + threadIdx.x;   // grid covers LNUM*HDIM = 4096
    if (i < LNUM * HDIM) { h0[i] = 0.f; c[i] = 0.f; }
    if (i < SDIM) xcur[i] = x[i];
}

// One LSTM layer, one timestep, fp16 weights + fp32 activations/accumulation.
// Block j computes gate rows {j, j+H, j+2H, j+3H}. Rows are 2048 halves =
// 256 uint4; thread t owns elements [8t, 8t+8).
__global__ __launch_bounds__(256) void lstm_layer_f16_kernel(
    const float* __restrict__ inp, const float* __restrict__ hin,
    float* __restrict__ hout, float* __restrict__ cst,
    const uint4* __restrict__ Wih, const uint4* __restrict__ Whh,
    const float* __restrict__ bih, const float* __restrict__ bhh)
{
    const int j = blockIdx.x;       // 0..HDIM-1
    const int t = threadIdx.x;      // 0..255

    const float4* inp4 = (const float4*)inp;
    const float4* hin4 = (const float4*)hin;
    const float4 x0 = inp4[2 * t], x1 = inp4[2 * t + 1];
    const float4 h0 = hin4[2 * t], h1 = hin4[2 * t + 1];

    float acc[4];
#pragma unroll
    for (int g = 0; g < 4; ++g) {
        const uint4* wi = Wih + ((size_t)(g * HDIM + j) << 8);
        const uint4* wh = Whh + ((size_t)(g * HDIM + j) << 8);
        uint4 a = wi[t], b = wh[t];
        float2 f;
        float s = 0.f;
        f = __half22float2(*(__half2*)&a.x); s += f.x * x0.x + f.y * x0.y;
        f = __half22float2(*(__half2*)&a.y); s += f.x * x0.z + f.y * x0.w;
        f = __half22float2(*(__half2*)&a.z); s += f.x * x1.x + f.y * x1.y;
        f = __half22float2(*(__half2*)&a.w); s += f.x * x1.z + f.y * x1.w;
        f = __half22float2(*(__half2*)&b.x); s += f.x * h0.x + f.y * h0.y;
        f = __half22float2(*(__half2*)&b.y); s += f.x * h0.z + f.y * h0.w;
        f = __half22float2(*(__half2*)&b.z); s += f.x * h1.x + f.y * h1.y;
        f = __half22float2(*(__half2*)&b.w); s += f.x * h1.z + f.y * h1.w;
        acc[g] = s;
    }

    __shared__ float red[4][4];     // [wave][gate]
    const int wave = t >> 6, lane = t & 63;
#pragma unroll
    for (int g = 0; g < 4; ++g) {
        float v = wave_sum(acc[g]);
        if (lane == 0) red[wave][g] = v;
    }
    __syncthreads();
    if (t == 0) {
        float gi = red[0][0] + red[1][0] + red[2][0] + red[3][0] + bih[0 * HDIM + j] + bhh[0 * HDIM + j];
        float gf = red[0][1] + red[1][1] + red[2][1] + red[3][1] + bih[1 * HDIM + j] + bhh[1 * HDIM + j];
        float gg = red[0][2] + red[1][2] + red[2][2] + red[3][2] + bih[2 * HDIM + j] + bhh[2 * HDIM + j];
        float go = red[0][3] + red[1][3] + red[2][3] + red[3][3] + bih[3 * HDIM + j] + bhh[3 * HDIM + j];
        float si = 1.f / (1.f + expf(-gi));
        float sf = 1.f / (1.f + expf(-gf));
        float so = 1.f / (1.f + expf(-go));
        float tg = tanhf(gg);
        float cn = sf * cst[j] + si * tg;
        cst[j]  = cn;
        hout[j] = so * tanhf(cn);
    }
}

// logits[r] = Wout16[r,:] @ h + bout[r]; one row per block, fp16 weights.
__global__ __launch_bounds__(256) void out_gemv_f16_kernel(
    const float* __restrict__ h, const uint4* __restrict__ Wout,
    const float* __restrict__ bout, float* __restrict__ logits)
{
    const int r = blockIdx.x, t = threadIdx.x;
    uint4 a = Wout[((size_t)r << 8) + t];
    const float4* h4 = (const float4*)h;
    const float4 h0 = h4[2 * t], h1 = h4[2 * t + 1];
    float2 f;
    float v = 0.f;
    f = __half22float2(*(__half2*)&a.x); v += f.x * h0.x + f.y * h0.y;
    f = __half22float2(*(__half2*)&a.y); v += f.x * h0.z + f.y * h0.w;
    f = __half22float2(*(__half2*)&a.z); v += f.x * h1.x + f.y * h1.y;
    f = __half22float2(*(__half2*)&a.w); v += f.x * h1.z + f.y * h1.w;
    __shared__ float red[4];
    v = wave_sum(v);
    if ((t & 63) == 0) red[t >> 6] = v;
    __syncthreads();
    if (t == 0) logits[r] = red[0] + red[1] + red[2] + red[3] + bout[r];
}

// Single-block softmax over 2048 logits; writes next input AND d_out[step].
__global__ __launch_bounds__(256) void softmax_kernel(
    const float* __restrict__ logits, float* __restrict__ xcur,
    float* __restrict__ outp)
{
    const int t = threadIdx.x;
    const float4* l4 = (const float4*)logits;
    float4 v0 = l4[t], v1 = l4[256 + t];

    float m = fmaxf(fmaxf(fmaxf(v0.x, v0.y), fmaxf(v0.z, v0.w)),
                    fmaxf(fmaxf(v1.x, v1.y), fmaxf(v1.z, v1.w)));
    __shared__ float red[4];
    __shared__ float bc;
    m = wave_max(m);
    if ((t & 63) == 0) red[t >> 6] = m;
    __syncthreads();
    if (t == 0) bc = fmaxf(fmaxf(red[0], red[1]), fmaxf(red[2], red[3]));
    __syncthreads();
    m = bc;

    float4 e0, e1;
    e0.x = expf(v0.x - m); e0.y = expf(v0.y - m); e0.z = expf(v0.z - m); e0.w = expf(v0.w - m);
    e1.x = expf(v1.x - m); e1.y = expf(v1.y - m); e1.z = expf(v1.z - m); e1.w = expf(v1.w - m);
    float s = e0.x + e0.y + e0.z + e0.w + e1.x + e1.y + e1.z + e1.w;
    s = wave_sum(s);
    if ((t & 63) == 0) red[t >> 6] = s;
    __syncthreads();
    if (t == 0) bc = red[0] + red[1] + red[2] + red[3];
    __syncthreads();
    const float inv = 1.f / bc;

    float4 p0, p1;
    p0.x = e0.x * inv; p0.y = e0.y * inv; p0.z = e0.z * inv; p0.w = e0.w * inv;
    p1.x = e1.x * inv; p1.y = e1.y * inv; p1.z = e1.z * inv; p1.w = e1.w * inv;
    ((float4*)xcur)[t]       = p0;
    ((float4*)xcur)[256 + t] = p1;
    ((float4*)outp)[t]       = p0;
    ((float4*)outp)[256 + t] = p1;
}

extern "C" void kernel_launch(void* const* d_in, const int* in_sizes, int n_in,
                              void* d_out, int out_size, void* d_ws, size_t ws_size,
                              hipStream_t stream) {
    const float* x    = (const float*)d_in[0];
    const float* Wih  = (const float*)d_in[1];   // [L, 4H, H] fp32
    const float* Whh  = (const float*)d_in[2];   // [L, 4H, H] fp32
    const float* bih  = (const float*)d_in[3];   // [L, 4H]
    const float* bhh  = (const float*)d_in[4];   // [L, 4H]
    const float* Wout = (const float*)d_in[5];   // [S, H] fp32
    const float* bout = (const float*)d_in[6];   // [S]
    float* out = (float*)d_out;                  // [A, S] fp32

    // Workspace layout: small fp32 state first (64 KiB), then fp16 weight copies.
    float* ws     = (float*)d_ws;
    float* xcur   = ws;                          // 2048
    float* hb     = ws + SDIM;                   // ping-pong h: 2 * L * H = 8192
    float* c      = hb + 2 * LNUM * HDIM;        // L * H = 4096
    float* logits = c + LNUM * HDIM;             // 2048

    const int  nW    = LNUM * 4 * HDIM * HDIM;   // 33554432 halves per W tensor
    const int  nWout = SDIM * HDIM;              // 4194304
    uint4* Wih16  = (uint4*)((char*)d_ws + 65536);
    uint4* Whh16  = Wih16 + nW / 8;              // + 4194304 uint4
    uint4* Wout16 = Whh16 + nW / 8;
    // total ws use: 65536 + 2*67108864 + 8388608 = ~142.7 MB (< 512 MB ws)

    const size_t lstride16 = (size_t)(4 * HDIM * HDIM) / 8;  // per-layer stride in uint4
    const size_t bstride   = (size_t)4 * HDIM;

    // Per-launch fp16 conversion (~61 us at 7 TB/s; paid once, saves ~143 MiB x16 in the steps)
    f32_to_f16_kernel<<<2048, 256, 0, stream>>>((const float4*)Wih, Wih16, nW / 8);
    f32_to_f16_kernel<<<2048, 256, 0, stream>>>((const float4*)Whh, Whh16, nW / 8);
    f32_to_f16_kernel<<<2048, 256, 0, stream>>>((const float4*)Wout, Wout16, nWout / 8);

    init_kernel<<<16, 256, 0, stream>>>(x, xcur, hb, c);

    for (int s = 0; s < ANUM; ++s) {
        const int cur = s & 1, nxt = cur ^ 1;
        float* h0in  = hb + cur * (LNUM * HDIM);
        float* h0out = hb + nxt * (LNUM * HDIM);
        float* h1in  = h0in + HDIM;
        float* h1out = h0out + HDIM;

        lstm_layer_f16_kernel<<<HDIM, 256, 0, stream>>>(
            xcur, h0in, h0out, c, Wih16, Whh16, bih, bhh);
        lstm_layer_f16_kernel<<<HDIM, 256, 0, stream>>>(
            h0out, h1in, h1out, c + HDIM,
            Wih16 + lstride16, Whh16 + lstride16, bih + bstride, bhh + bstride);
        out_gemv_f16_kernel<<<SDIM, 256, 0, stream>>>(h1out, Wout16, bout, logits);
        softmax_kernel<<<1, 256, 0, stream>>>(logits, xcur, out + (size_t)s * SDIM);
    }
}

// Round 3
// 588.644 us; speedup vs baseline: 1.4087x; 1.0624x over previous
//
#include <hip/hip_runtime.h>
#include <hip/hip_fp16.h>
#include <math.h>

#define SDIM 2048
#define HDIM 2048
#define LNUM 2
#define ANUM 16

typedef float f32x4 __attribute__((ext_vector_type(4)));

__device__ __forceinline__ float wave_sum(float v) {
#pragma unroll
    for (int off = 32; off > 0; off >>= 1) v += __shfl_down(v, off, 64);
    return v;
}

__device__ __forceinline__ float wave_max(float v) {
#pragma unroll
    for (int off = 32; off > 0; off >>= 1) v = fmaxf(v, __shfl_down(v, off, 64));
    return v;
}

__device__ __forceinline__ uint4 pack8_f16(f32x4 a, f32x4 b) {
    __half2 p0 = __floats2half2_rn(a.x, a.y);
    __half2 p1 = __floats2half2_rn(a.z, a.w);
    __half2 p2 = __floats2half2_rn(b.x, b.y);
    __half2 p3 = __floats2half2_rn(b.z, b.w);
    uint4 o;
    o.x = *(unsigned int*)&p0; o.y = *(unsigned int*)&p1;
    o.z = *(unsigned int*)&p2; o.w = *(unsigned int*)&p3;
    return o;
}

__device__ __forceinline__ float dotv(f32x4 a, f32x4 b) {
    return a.x * b.x + a.y * b.y + a.z * b.z + a.w * b.w;
}

// Zero h (ping buffer 0) and c. Workspace is poisoned 0xAA; init everything read.
__global__ __launch_bounds__(256) void init_kernel(float* __restrict__ h0,
                                                   float* __restrict__ c)
{
    int i = blockIdx.x * 256 + threadIdx.x;   // grid covers LNUM*HDIM = 4096
    if (i < LNUM * HDIM) { h0[i] = 0.f; c[i] = 0.f; }
}

// One LSTM layer, one timestep. Block j computes gate rows {j, j+H, j+2H, j+3H}.
// CONV: read fp32 weights (non-temporal), write fp16 copy for later steps.
// SMAX: input vector = softmax(logits) computed in-block; block 0 also writes
//       it to out_prev (this is out[s-1] of the autoregressive sequence).
template<bool CONV, bool SMAX>
__global__ __launch_bounds__(256) void lstm_kernel(
    const float* __restrict__ inp_direct,   // used if !SMAX
    const float* __restrict__ logits,       // used if SMAX
    float* __restrict__ out_prev,           // used if SMAX (block 0 writes)
    const float* __restrict__ hin, float* __restrict__ hout,
    float* __restrict__ cst,
    const float* __restrict__ Wih32, const float* __restrict__ Whh32,  // CONV read
    const uint4* __restrict__ Wih16r, const uint4* __restrict__ Whh16r,// !CONV read
    uint4* __restrict__ Wih16w, uint4* __restrict__ Whh16w,            // CONV write
    const float* __restrict__ bih, const float* __restrict__ bhh)
{
    const int j = blockIdx.x;       // 0..HDIM-1
    const int t = threadIdx.x;      // 0..255
    const int wave = t >> 6, lane = t & 63;

    __shared__ float red[4][4];     // [wave][gate] — reused for softmax reduces
    __shared__ float sbc;

    // ---- input vector (8 floats per thread) ----
    f32x4 x0, x1;
    if (SMAX) {
        const f32x4* l4 = (const f32x4*)logits;
        f32x4 v0 = l4[2 * t], v1 = l4[2 * t + 1];
        float m = fmaxf(fmaxf(fmaxf(v0.x, v0.y), fmaxf(v0.z, v0.w)),
                        fmaxf(fmaxf(v1.x, v1.y), fmaxf(v1.z, v1.w)));
        m = wave_max(m);
        if (lane == 0) red[wave][0] = m;
        __syncthreads();
        if (t == 0) sbc = fmaxf(fmaxf(red[0][0], red[1][0]), fmaxf(red[2][0], red[3][0]));
        __syncthreads();
        m = sbc;
        f32x4 e0, e1;
        e0.x = expf(v0.x - m); e0.y = expf(v0.y - m); e0.z = expf(v0.z - m); e0.w = expf(v0.w - m);
        e1.x = expf(v1.x - m); e1.y = expf(v1.y - m); e1.z = expf(v1.z - m); e1.w = expf(v1.w - m);
        float s = e0.x + e0.y + e0.z + e0.w + e1.x + e1.y + e1.z + e1.w;
        s = wave_sum(s);
        if (lane == 0) red[wave][0] = s;
        __syncthreads();
        if (t == 0) sbc = red[0][0] + red[1][0] + red[2][0] + red[3][0];
        __syncthreads();
        const float inv = 1.f / sbc;
        x0 = e0 * inv;
        x1 = e1 * inv;
        if (blockIdx.x == 0) {
            ((f32x4*)out_prev)[2 * t]     = x0;
            ((f32x4*)out_prev)[2 * t + 1] = x1;
        }
        __syncthreads();   // red[] reused below
    } else {
        const f32x4* inp4 = (const f32x4*)inp_direct;
        x0 = inp4[2 * t]; x1 = inp4[2 * t + 1];
    }

    const f32x4* hin4 = (const f32x4*)hin;
    const f32x4 h0 = hin4[2 * t], h1 = hin4[2 * t + 1];

    // ---- 4 gate-row dot products ----
    float acc[4];
#pragma unroll
    for (int g = 0; g < 4; ++g) {
        const int row = g * HDIM + j;
        float s = 0.f;
        if (CONV) {
            const f32x4* wi = (const f32x4*)(Wih32 + (size_t)row * HDIM);
            const f32x4* wh = (const f32x4*)(Whh32 + (size_t)row * HDIM);
            f32x4 wa = __builtin_nontemporal_load(wi + 2 * t);
            f32x4 wb = __builtin_nontemporal_load(wi + 2 * t + 1);
            f32x4 wc = __builtin_nontemporal_load(wh + 2 * t);
            f32x4 wd = __builtin_nontemporal_load(wh + 2 * t + 1);
            s = dotv(wa, x0) + dotv(wb, x1) + dotv(wc, h0) + dotv(wd, h1);
            Wih16w[(size_t)row * 256 + t] = pack8_f16(wa, wb);
            Whh16w[(size_t)row * 256 + t] = pack8_f16(wc, wd);
        } else {
            uint4 a = Wih16r[(size_t)row * 256 + t];
            uint4 b = Whh16r[(size_t)row * 256 + t];
            float2 f;
            f = __half22float2(*(__half2*)&a.x); s += f.x * x0.x + f.y * x0.y;
            f = __half22float2(*(__half2*)&a.y); s += f.x * x0.z + f.y * x0.w;
            f = __half22float2(*(__half2*)&a.z); s += f.x * x1.x + f.y * x1.y;
            f = __half22float2(*(__half2*)&a.w); s += f.x * x1.z + f.y * x1.w;
            f = __half22float2(*(__half2*)&b.x); s += f.x * h0.x + f.y * h0.y;
            f = __half22float2(*(__half2*)&b.y); s += f.x * h0.z + f.y * h0.w;
            f = __half22float2(*(__half2*)&b.z); s += f.x * h1.x + f.y * h1.y;
            f = __half22float2(*(__half2*)&b.w); s += f.x * h1.z + f.y * h1.w;
        }
        acc[g] = s;
    }

#pragma unroll
    for (int g = 0; g < 4; ++g) {
        float v = wave_sum(acc[g]);
        if (lane == 0) red[wave][g] = v;
    }
    __syncthreads();
    if (t == 0) {
        float gi = red[0][0] + red[1][0] + red[2][0] + red[3][0] + bih[0 * HDIM + j] + bhh[0 * HDIM + j];
        float gf = red[0][1] + red[1][1] + red[2][1] + red[3][1] + bih[1 * HDIM + j] + bhh[1 * HDIM + j];
        float gg = red[0][2] + red[1][2] + red[2][2] + red[3][2] + bih[2 * HDIM + j] + bhh[2 * HDIM + j];
        float go = red[0][3] + red[1][3] + red[2][3] + red[3][3] + bih[3 * HDIM + j] + bhh[3 * HDIM + j];
        float si = 1.f / (1.f + expf(-gi));
        float sf = 1.f / (1.f + expf(-gf));
        float so = 1.f / (1.f + expf(-go));
        float tg = tanhf(gg);
        float cn = sf * cst[j] + si * tg;
        cst[j]  = cn;
        hout[j] = so * tanhf(cn);
    }
}

// logits[r] = Wout[r,:] @ h + bout[r]; one row per block.
// CONV: read fp32 (non-temporal) + write fp16 copy.
template<bool CONV>
__global__ __launch_bounds__(256) void out_gemv_kernel(
    const float* __restrict__ h,
    const float* __restrict__ Wout32, const uint4* __restrict__ Wout16r,
    uint4* __restrict__ Wout16w,
    const float* __restrict__ bout, float* __restrict__ logits)
{
    const int r = blockIdx.x, t = threadIdx.x;
    const f32x4* h4 = (const f32x4*)h;
    const f32x4 h0 = h4[2 * t], h1 = h4[2 * t + 1];
    float v = 0.f;
    if (CONV) {
        const f32x4* w = (const f32x4*)(Wout32 + (size_t)r * HDIM);
        f32x4 wa = __builtin_nontemporal_load(w + 2 * t);
        f32x4 wb = __builtin_nontemporal_load(w + 2 * t + 1);
        v = dotv(wa, h0) + dotv(wb, h1);
        Wout16w[(size_t)r * 256 + t] = pack8_f16(wa, wb);
    } else {
        uint4 a = Wout16r[(size_t)r * 256 + t];
        float2 f;
        f = __half22float2(*(__half2*)&a.x); v += f.x * h0.x + f.y * h0.y;
        f = __half22float2(*(__half2*)&a.y); v += f.x * h0.z + f.y * h0.w;
        f = __half22float2(*(__half2*)&a.z); v += f.x * h1.x + f.y * h1.y;
        f = __half22float2(*(__half2*)&a.w); v += f.x * h1.z + f.y * h1.w;
    }
    __shared__ float red[4];
    v = wave_sum(v);
    if ((t & 63) == 0) red[t >> 6] = v;
    __syncthreads();
    if (t == 0) logits[r] = red[0] + red[1] + red[2] + red[3] + bout[r];
}

// Standalone softmax for the final step's output only.
__global__ __launch_bounds__(256) void softmax_out_kernel(
    const float* __restrict__ logits, float* __restrict__ outp)
{
    const int t = threadIdx.x;
    const f32x4* l4 = (const f32x4*)logits;
    f32x4 v0 = l4[2 * t], v1 = l4[2 * t + 1];
    float m = fmaxf(fmaxf(fmaxf(v0.x, v0.y), fmaxf(v0.z, v0.w)),
                    fmaxf(fmaxf(v1.x, v1.y), fmaxf(v1.z, v1.w)));
    __shared__ float red[4];
    __shared__ float bc;
    m = wave_max(m);
    if ((t & 63) == 0) red[t >> 6] = m;
    __syncthreads();
    if (t == 0) bc = fmaxf(fmaxf(red[0], red[1]), fmaxf(red[2], red[3]));
    __syncthreads();
    m = bc;
    f32x4 e0, e1;
    e0.x = expf(v0.x - m); e0.y = expf(v0.y - m); e0.z = expf(v0.z - m); e0.w = expf(v0.w - m);
    e1.x = expf(v1.x - m); e1.y = expf(v1.y - m); e1.z = expf(v1.z - m); e1.w = expf(v1.w - m);
    float s = e0.x + e0.y + e0.z + e0.w + e1.x + e1.y + e1.z + e1.w;
    s = wave_sum(s);
    if ((t & 63) == 0) red[t >> 6] = s;
    __syncthreads();
    if (t == 0) bc = red[0] + red[1] + red[2] + red[3];
    __syncthreads();
    const float inv = 1.f / bc;
    ((f32x4*)outp)[2 * t]     = e0 * inv;
    ((f32x4*)outp)[2 * t + 1] = e1 * inv;
}

extern "C" void kernel_launch(void* const* d_in, const int* in_sizes, int n_in,
                              void* d_out, int out_size, void* d_ws, size_t ws_size,
                              hipStream_t stream) {
    const float* x    = (const float*)d_in[0];
    const float* Wih  = (const float*)d_in[1];   // [L, 4H, H] fp32
    const float* Whh  = (const float*)d_in[2];   // [L, 4H, H] fp32
    const float* bih  = (const float*)d_in[3];   // [L, 4H]
    const float* bhh  = (const float*)d_in[4];   // [L, 4H]
    const float* Wout = (const float*)d_in[5];   // [S, H] fp32
    const float* bout = (const float*)d_in[6];   // [S]
    float* out = (float*)d_out;                  // [A, S] fp32

    // Workspace: small fp32 state first (64 KiB), then fp16 weight copies.
    float* ws     = (float*)d_ws;
    float* hb     = ws;                          // ping-pong h: 2 * L * H = 8192
    float* c      = hb + 2 * LNUM * HDIM;        // L * H = 4096
    float* logits = c + LNUM * HDIM;             // 2048

    const int nW = LNUM * 4 * HDIM * HDIM;       // halves per W tensor
    uint4* Wih16  = (uint4*)((char*)d_ws + 65536);
    uint4* Whh16  = Wih16 + nW / 8;
    uint4* Wout16 = Whh16 + nW / 8;
    // ws use: 64 KiB + 2*64 MiB + 8 MiB fp16 ≈ 136 MiB

    const size_t wstride32 = (size_t)4 * HDIM * HDIM;        // fp32 per-layer stride
    const size_t lstride16 = (size_t)(4 * HDIM * HDIM) / 8;  // uint4 per-layer stride
    const size_t bstride   = (size_t)4 * HDIM;

    init_kernel<<<16, 256, 0, stream>>>(hb, c);

    for (int s = 0; s < ANUM; ++s) {
        const int cur = s & 1, nxt = cur ^ 1;
        float* h0in  = hb + cur * (LNUM * HDIM);
        float* h0out = hb + nxt * (LNUM * HDIM);
        float* h1in  = h0in + HDIM;
        float* h1out = h0out + HDIM;

        if (s == 0) {
            // Step 0: fp32 weights (non-temporal reads), writes fp16 copies.
            lstm_kernel<true, false><<<HDIM, 256, 0, stream>>>(
                x, nullptr, nullptr, h0in, h0out, c,
                Wih, Whh, nullptr, nullptr, Wih16, Whh16, bih, bhh);
            lstm_kernel<true, false><<<HDIM, 256, 0, stream>>>(
                h0out, nullptr, nullptr, h1in, h1out, c + HDIM,
                Wih + wstride32, Whh + wstride32, nullptr, nullptr,
                Wih16 + lstride16, Whh16 + lstride16, bih + bstride, bhh + bstride);
            out_gemv_kernel<true><<<SDIM, 256, 0, stream>>>(
                h1out, Wout, nullptr, Wout16, bout, logits);
        } else {
            // Steps 1..15: fp16 weights; layer 0 computes softmax(logits) as its
            // input and block 0 writes it to out[s-1].
            lstm_kernel<false, true><<<HDIM, 256, 0, stream>>>(
                nullptr, logits, out + (size_t)(s - 1) * SDIM, h0in, h0out, c,
                nullptr, nullptr, Wih16, Whh16, nullptr, nullptr, bih, bhh);
            lstm_kernel<false, false><<<HDIM, 256, 0, stream>>>(
                h0out, nullptr, nullptr, h1in, h1out, c + HDIM,
                nullptr, nullptr, Wih16 + lstride16, Whh16 + lstride16,
                nullptr, nullptr, bih + bstride, bhh + bstride);
            out_gemv_kernel<false><<<SDIM, 256, 0, stream>>>(
                h1out, nullptr, Wout16, nullptr, bout, logits);
        }
    }
    softmax_out_kernel<<<1, 256, 0, stream>>>(logits, out + (size_t)(ANUM - 1) * SDIM);
}